// Round 10
// baseline (218.202 us; speedup 1.0000x reference)
//
#include <hip/hip_runtime.h>
#include <hip/hip_bf16.h>

// y = (softmax((xWq)(xWk)^T/8) + B) @ (xWv); b=2 s=2048 d=1024 h=16 hd=64
// conv_x -> wtrans -> qkv_gemm (NEW: 256^2 tile, BK=32, 4-deep LDS ring,
//   counted vmcnt(8) never-drain, 32 MFMA per barrier/wave) -> attn (R7 exact)

typedef __attribute__((ext_vector_type(4))) float  f32x4;
typedef __attribute__((ext_vector_type(8))) short  bf16x8;
typedef __attribute__((ext_vector_type(4))) short  s16x4;
typedef __attribute__((ext_vector_type(4))) unsigned u32x4;

__device__ __forceinline__ short f2bf(float f) {
    __hip_bfloat16 h = __float2bfloat16(f);
    return __builtin_bit_cast(short, h);
}

__device__ __forceinline__ unsigned cvt_pk_bf16(float lo, float hi) {
    unsigned w;
    asm("v_cvt_pk_bf16_f32 %0, %1, %2" : "=v"(w) : "v"(lo), "v"(hi));
    return w;
}

__device__ __forceinline__ bf16x8 pack8(f32x4 a, f32x4 b) {
    u32x4 t = (u32x4){cvt_pk_bf16(a[0], a[1]), cvt_pk_bf16(a[2], a[3]),
                      cvt_pk_bf16(b[0], b[1]), cvt_pk_bf16(b[2], b[3])};
    return __builtin_bit_cast(bf16x8, t);
}

__device__ __forceinline__ void gll16(const short* g, short* l) {
    __builtin_amdgcn_global_load_lds(
        (const __attribute__((address_space(1))) void*)g,
        (__attribute__((address_space(3))) void*)l, 16, 0, 0);
}

// ---------------- conv_x ----------------
__global__ void conv_x_kernel(const float* __restrict__ x, short* __restrict__ xb) {
    int idx = blockIdx.x * 256 + threadIdx.x;
    f32x4 v = *reinterpret_cast<const f32x4*>(x + (size_t)idx * 4);
    s16x4 o;
    o[0] = f2bf(v[0]); o[1] = f2bf(v[1]); o[2] = f2bf(v[2]); o[3] = f2bf(v[3]);
    *reinterpret_cast<s16x4*>(xb + (size_t)idx * 4) = o;
}

// ---------------- wtrans ----------------
__global__ void wtrans_kernel(const float* __restrict__ W, short* __restrict__ Wt) {
    __shared__ float tile[64][65];
    int kb = blockIdx.x, nb = blockIdx.y;
    int t = threadIdx.x;
    int c4 = (t & 15) * 4;
    int r0 = t >> 4;
#pragma unroll
    for (int rr = 0; rr < 4; ++rr) {
        int kl = r0 + rr * 16;
        f32x4 v = *reinterpret_cast<const f32x4*>(W + (size_t)(kb * 64 + kl) * 3072 + nb * 64 + c4);
        tile[kl][c4 + 0] = v[0]; tile[kl][c4 + 1] = v[1];
        tile[kl][c4 + 2] = v[2]; tile[kl][c4 + 3] = v[3];
    }
    __syncthreads();
#pragma unroll
    for (int rr = 0; rr < 4; ++rr) {
        int nl = r0 + rr * 16;
        s16x4 o;
#pragma unroll
        for (int i = 0; i < 4; ++i) o[i] = f2bf(tile[c4 + i][nl]);
        *reinterpret_cast<s16x4*>(Wt + (size_t)(nb * 64 + nl) * 1024 + kb * 64 + c4) = o;
    }
}

// ---------------- qkv_gemm: 256x256 tile, BK=32, 4-deep ring ----------------
// M=4096, N=3072, K=1024. Grid 192 (16 bm x 12 bn, XCD-swizzled), 512 thr.
// 8 waves = 2(M) x 4(N); per-wave output 128x64 (acc[8][4] f32x4).
// Per K-tile (32 tiles): stage tile t+3 (4 gll16/thr), 12 ds_read_b128,
// 32 MFMA, vmcnt(8) [tail 4/0], 1 barrier. LDS = 4*(16+16) KB = 128 KB.
__global__ __launch_bounds__(512, 2) void qkv_gemm_kernel(
    const short* __restrict__ xb, const short* __restrict__ Wt,
    const float* __restrict__ bias,
    short* __restrict__ Qo, short* __restrict__ Ko, short* __restrict__ Vto)
{
    __shared__ short As[4][256 * 32];
    __shared__ short Bs[4][256 * 32];

    int id = blockIdx.x;
    int wg = (id & 7) * 24 + (id >> 3);   // bijective XCD clustering (192 = 8*24)
    int bm = wg & 15;
    int bn = wg >> 4;

    int tid = threadIdx.x;
    int wave = tid >> 6, lane = tid & 63, g = lane >> 4, lr = lane & 15;
    int wr = wave >> 2, wc = wave & 3;    // 2 x 4 wave grid

    f32x4 acc[8][4];
#pragma unroll
    for (int m = 0; m < 8; ++m)
#pragma unroll
        for (int n = 0; n < 4; ++n) acc[m][n] = (f32x4){0.f, 0.f, 0.f, 0.f};

#define STAGE(buf, tt) do {                                                       \
    _Pragma("unroll")                                                             \
    for (int j = 0; j < 2; ++j) {                                                 \
        int c = j * 512 + tid;            /* chunk 0..1023 (16B each) */          \
        int row = c >> 2, ch = c & 3;                                             \
        int scc = (ch ^ ((row + (row >> 2)) & 3)) * 8;                            \
        gll16(xb + (size_t)(bm * 256 + row) * 1024 + (tt) * 32 + scc,             \
              &As[buf][(j * 512 + wave * 64) * 8]);                               \
        gll16(Wt + (size_t)(bn * 256 + row) * 1024 + (tt) * 32 + scc,             \
              &Bs[buf][(j * 512 + wave * 64) * 8]);                               \
    }                                                                             \
} while (0)

    // prologue: stage tiles 0,1,2 (12 loads/thr); tile0 = oldest 4 -> vmcnt(8)
    STAGE(0, 0);
    STAGE(1, 1);
    STAGE(2, 2);
    __builtin_amdgcn_sched_barrier(0);
    asm volatile("s_waitcnt vmcnt(8)" ::: "memory");
    __builtin_amdgcn_s_barrier();
    __builtin_amdgcn_sched_barrier(0);

    for (int t = 0; t < 32; ++t) {
        int buf = t & 3;
        if (t <= 28) STAGE((t + 3) & 3, t + 3);
        __builtin_amdgcn_sched_barrier(0);

        bf16x8 a[8], bq[4];
#pragma unroll
        for (int m = 0; m < 8; ++m) {
            int row = wr * 128 + m * 16 + lr;
            a[m] = *reinterpret_cast<const bf16x8*>(
                &As[buf][row * 32 + ((g ^ ((row + (row >> 2)) & 3)) * 8)]);
        }
#pragma unroll
        for (int n = 0; n < 4; ++n) {
            int row = wc * 64 + n * 16 + lr;
            bq[n] = *reinterpret_cast<const bf16x8*>(
                &Bs[buf][row * 32 + ((g ^ ((row + (row >> 2)) & 3)) * 8)]);
        }

        __builtin_amdgcn_s_setprio(1);
#pragma unroll
        for (int m = 0; m < 8; ++m)
#pragma unroll
            for (int n = 0; n < 4; ++n)
                acc[m][n] = __builtin_amdgcn_mfma_f32_16x16x32_bf16(a[m], bq[n], acc[m][n], 0, 0, 0);
        __builtin_amdgcn_s_setprio(0);

        if (t <= 28)      { asm volatile("s_waitcnt vmcnt(8)" ::: "memory"); }
        else if (t == 29) { asm volatile("s_waitcnt vmcnt(4)" ::: "memory"); }
        else if (t == 30) { asm volatile("s_waitcnt vmcnt(0)" ::: "memory"); }
        if (t < 31) {
            __builtin_amdgcn_s_barrier();
            __builtin_amdgcn_sched_barrier(0);
        }
    }
#undef STAGE

    // epilogue: bias add, scatter Q/K (row-major [bh][s][64]) and Vt ([bh][64][s])
#pragma unroll
    for (int n = 0; n < 4; ++n) {
        int ncol = bn * 256 + wc * 64 + n * 16 + lr;
        float bv = bias[ncol];
        int which = ncol >> 10;
        int h = (ncol >> 6) & 15;
        int dd = ncol & 63;
#pragma unroll
        for (int m = 0; m < 8; ++m) {
            int m0 = bm * 256 + wr * 128 + m * 16 + g * 4;
            int bb = m0 >> 11, s0 = m0 & 2047;
            if (which == 2) {
                s16x4 o;
#pragma unroll
                for (int r = 0; r < 4; ++r) o[r] = f2bf(acc[m][n][r] + bv);
                *reinterpret_cast<s16x4*>(
                    Vto + ((size_t)(bb * 16 + h) * 64 + dd) * 2048 + s0) = o;
            } else {
                short* base = (which == 0) ? Qo : Ko;
#pragma unroll
                for (int r = 0; r < 4; ++r)
                    base[(((size_t)bb * 16 + h) * 2048 + s0 + r) * 64 + dd] =
                        f2bf(acc[m][n][r] + bv);
            }
        }
    }
}

// ---------------- attn (R7 verbatim) ----------------
__global__ __launch_bounds__(512, 4) void attn_kernel(
    const short* __restrict__ Qw, const short* __restrict__ Kw, const short* __restrict__ Vtw,
    const float* __restrict__ attnB, float* __restrict__ out)
{
    __shared__ short Ks [2][64 * 64];
    __shared__ short Vts[2][64 * 64];
    __shared__ short Ps [8][16 * 64];

    int id = blockIdx.x;
    int bh3 = id & 7;
    int qt  = (id >> 3) & 15;
    int bh  = ((id >> 7) << 3) | bh3;
    int b = bh >> 4, h = bh & 15;
    int tid = threadIdx.x;
    int wave = tid >> 6, lane = tid & 63, g = lane >> 4, lr = lane & 15;

    const short* Qb = Qw  + (size_t)bh * 2048 * 64;
    const short* Kb = Kw  + (size_t)bh * 2048 * 64;
    const short* Vb = Vtw + (size_t)bh * 64 * 2048;
    const float* Bp = attnB + (size_t)bh * 2048 * 2048;

    int qbase = qt * 128 + wave * 16;

    bf16x8 qf0, qf1;
    {
        const short* qp = Qb + (size_t)(qbase + lr) * 64 + g * 8;
        qf0 = *reinterpret_cast<const bf16x8*>(qp);
        qf1 = *reinterpret_cast<const bf16x8*>(qp + 32);
    }
    const float* brow = Bp + (size_t)(qbase + lr) * 2048 + g * 8;

    f32x4 Os[4], Ob[4];
#pragma unroll
    for (int dt = 0; dt < 4; ++dt) { Os[dt] = (f32x4){0.f,0.f,0.f,0.f}; Ob[dt] = (f32x4){0.f,0.f,0.f,0.f}; }
    float lsum = 0.f;

#define STAGE_KV(buf, ktt) do {                                                   \
    int row = tid >> 3, cc = tid & 7;                                             \
    int scc = (cc ^ (row & 7)) * 8;                                               \
    gll16(Kb + (size_t)((ktt) * 64 + row) * 64 + scc,                             \
          &Ks[buf][wave * 512]);                                                  \
    gll16(Vb + (size_t)row * 2048 + (ktt) * 64 + scc,                             \
          &Vts[buf][wave * 512]);                                                 \
} while (0)

#define LOADB(d0, d1, d2, d3, ktt) do {                                           \
    const float* bp_ = brow + (size_t)(ktt) * 64;                                 \
    d0 = *reinterpret_cast<const f32x4*>(bp_);                                    \
    d1 = *reinterpret_cast<const f32x4*>(bp_ + 4);                                \
    d2 = *reinterpret_cast<const f32x4*>(bp_ + 32);                               \
    d3 = *reinterpret_cast<const f32x4*>(bp_ + 36);                               \
} while (0)

#define COMPUTE(cur, xb0, xb1) do {                                               \
    f32x4 S[4];                                                                   \
    __builtin_amdgcn_s_setprio(1);                                                \
    _Pragma("unroll")                                                             \
    for (int nt = 0; nt < 4; ++nt) {                                              \
        int row = nt * 16 + lr;                                                   \
        bf16x8 kf0 = *reinterpret_cast<const bf16x8*>(&Ks[cur][row * 64 + (((g    ) ^ (lr & 7)) * 8)]); \
        bf16x8 kf1 = *reinterpret_cast<const bf16x8*>(&Ks[cur][row * 64 + (((g + 4) ^ (lr & 7)) * 8)]); \
        f32x4 s = (f32x4){0.f,0.f,0.f,0.f};                                       \
        s = __builtin_amdgcn_mfma_f32_16x16x32_bf16(kf0, qf0, s, 0, 0, 0);        \
        s = __builtin_amdgcn_mfma_f32_16x16x32_bf16(kf1, qf1, s, 0, 0, 0);        \
        S[nt] = s;                                                                \
    }                                                                             \
    __builtin_amdgcn_s_setprio(0);                                                \
    _Pragma("unroll")                                                             \
    for (int nt = 0; nt < 4; ++nt)                                                \
        _Pragma("unroll")                                                         \
        for (int r = 0; r < 4; ++r) {                                             \
            float p = exp2f(S[nt][r] * 0.1803368801111f);                         \
            S[nt][r] = p;                                                         \
            lsum += p;                                                            \
        }                                                                         \
    short* psw = &Ps[wave][lr * 64];                                              \
    _Pragma("unroll")                                                             \
    for (int nt = 0; nt < 4; ++nt)                                                \
        _Pragma("unroll")                                                         \
        for (int rp = 0; rp < 2; ++rp) {                                          \
            unsigned w = cvt_pk_bf16(S[nt][2 * rp], S[nt][2 * rp + 1]);           \
            int kp = 8 * nt + 2 * g + rp;                                         \
            int bi = kp >> 2, off = kp & 3;                                       \
            *reinterpret_cast<unsigned*>(psw + ((bi ^ (lr & 7)) << 3) + off * 2) = w; \
        }                                                                         \
    bf16x8 pf0 = *reinterpret_cast<const bf16x8*>(&Ps[wave][lr * 64 + (((g    ) ^ (lr & 7)) * 8)]); \
    bf16x8 pf1 = *reinterpret_cast<const bf16x8*>(&Ps[wave][lr * 64 + (((g + 4) ^ (lr & 7)) * 8)]); \
    __builtin_amdgcn_s_setprio(1);                                                \
    _Pragma("unroll")                                                             \
    for (int dt = 0; dt < 4; ++dt) {                                              \
        int row = dt * 16 + lr;                                                   \
        bf16x8 v0 = *reinterpret_cast<const bf16x8*>(&Vts[cur][row * 64 + (((g    ) ^ (lr & 7)) * 8)]); \
        bf16x8 v1 = *reinterpret_cast<const bf16x8*>(&Vts[cur][row * 64 + (((g + 4) ^ (lr & 7)) * 8)]); \
        Os[dt] = __builtin_amdgcn_mfma_f32_16x16x32_bf16(pf0, v0, Os[dt], 0, 0, 0); \
        Os[dt] = __builtin_amdgcn_mfma_f32_16x16x32_bf16(pf1, v1, Os[dt], 0, 0, 0); \
        Ob[dt] = __builtin_amdgcn_mfma_f32_16x16x32_bf16(xb0, v0, Ob[dt], 0, 0, 0); \
        Ob[dt] = __builtin_amdgcn_mfma_f32_16x16x32_bf16(xb1, v1, Ob[dt], 0, 0, 0); \
    }                                                                             \
    __builtin_amdgcn_s_setprio(0);                                                \
} while (0)

    f32x4 a0, a1, a2, a3, p0, p1, p2, p3;

    STAGE_KV(0, 0);
    __builtin_amdgcn_sched_barrier(0);
    LOADB(a0, a1, a2, a3, 0);
    LOADB(p0, p1, p2, p3, 1);
    __builtin_amdgcn_sched_barrier(0);
    asm volatile("s_waitcnt vmcnt(8)" ::: "memory");
    __builtin_amdgcn_s_barrier();
    __builtin_amdgcn_sched_barrier(0);

    for (int t = 0; t < 16; ++t) {
        {
            bf16x8 bbf0 = pack8(a0, a1);
            bf16x8 bbf1 = pack8(a2, a3);
            STAGE_KV(1, 2 * t + 1);
            __builtin_amdgcn_sched_barrier(0);
            if (t < 15) LOADB(a0, a1, a2, a3, 2 * t + 2);
            __builtin_amdgcn_sched_barrier(0);
            COMPUTE(0, bbf0, bbf1);
            if (t < 15) {
                asm volatile("s_waitcnt vmcnt(4)" ::: "memory");
            } else {
                asm volatile("s_waitcnt vmcnt(0)" ::: "memory");
            }
            __builtin_amdgcn_s_barrier();
            __builtin_amdgcn_sched_barrier(0);
        }
        {
            bf16x8 bbf0 = pack8(p0, p1);
            bf16x8 bbf1 = pack8(p2, p3);
            if (t < 15) {
                STAGE_KV(0, 2 * t + 2);
                __builtin_amdgcn_sched_barrier(0);
                LOADB(p0, p1, p2, p3, 2 * t + 3);
                __builtin_amdgcn_sched_barrier(0);
            }
            COMPUTE(1, bbf0, bbf1);
            if (t < 15) {
                asm volatile("s_waitcnt vmcnt(4)" ::: "memory");
                __builtin_amdgcn_s_barrier();
                __builtin_amdgcn_sched_barrier(0);
            }
        }
    }
#undef STAGE_KV
#undef LOADB
#undef COMPUTE

    float l = lsum;
    l += __shfl_xor(l, 16);
    l += __shfl_xor(l, 32);
    float inv = 1.0f / l;
#pragma unroll
    for (int r = 0; r < 4; ++r) {
        float invr = __shfl(inv, g * 4 + r);
        int q = qbase + g * 4 + r;
#pragma unroll
        for (int dt = 0; dt < 4; ++dt) {
            int dcol = dt * 16 + lr;
            float v = Os[dt][r] * invr + Ob[dt][r];
            __builtin_nontemporal_store(v, &out[((size_t)(b * 2048 + q) * 16 + h) * 64 + dcol]);
        }
    }
}

extern "C" void kernel_launch(void* const* d_in, const int* in_sizes, int n_in,
                              void* d_out, int out_size, void* d_ws, size_t ws_size,
                              hipStream_t stream) {
    const float* x     = (const float*)d_in[0];
    const float* attnB = (const float*)d_in[1];
    const float* W     = (const float*)d_in[2];
    const float* bias  = (const float*)d_in[3];
    float* out = (float*)d_out;

    short* ws = (short*)d_ws;
    short* xb = ws;                // 4,194,304 shorts
    short* Wt = xb + 4194304;      // 3,145,728
    short* Q  = Wt + 3145728;      // 4,194,304
    short* K  = Q  + 4194304;      // 4,194,304
    short* Vt = K  + 4194304;      // 4,194,304

    conv_x_kernel<<<4096, 256, 0, stream>>>(x, xb);
    wtrans_kernel<<<dim3(16, 48), 256, 0, stream>>>(W, Wt);
    qkv_gemm_kernel<<<192, 512, 0, stream>>>(xb, Wt, bias, Q, K, Vt);
    attn_kernel<<<512, 512, 0, stream>>>(Q, K, Vt, attnB, out);
}